// Round 3
// baseline (960.086 us; speedup 1.0000x reference)
//
#include <hip/hip_runtime.h>
#include <hip/hip_bf16.h>
#include <math.h>

#define T_ 512
#define N_ 32
#define D_ 300
#define R_ 3
#define E_ 64
#define VG_ 40000

typedef __attribute__((ext_vector_type(8))) short bf16x8;
typedef __attribute__((ext_vector_type(4))) float f32x4;

// barrier with lgkm-only wait (raw asm barrier: the memory legalizer does not see
// this as __syncthreads, so NO vmcnt drain is forced here — global prefetch loads
// stay in flight across the barrier and drain at their use point next step)
#define LGKM_BARRIER() asm volatile("s_waitcnt lgkmcnt(0)\n\ts_barrier" ::: "memory")

static __device__ inline unsigned short f2b(float f) {
  __hip_bfloat16 h = __float2bfloat16(f);
  return *(unsigned short*)&h;
}

// ---------------- zero ----------------
__global__ void k_zero(float* __restrict__ p, int n) {
  int i = blockIdx.x * blockDim.x + threadIdx.x;
  if (i < n) p[i] = 0.f;
}

// ---------------- transpose Wu [9600,300] -> Wu_t bf16 [384][9600] ----------------
__global__ void k_tr_wu(const float* __restrict__ Wu, unsigned short* __restrict__ Wt) {
  __shared__ float s[32][33];
  int kb = blockIdx.x * 32, nb = blockIdx.y * 32;
  int tn = threadIdx.x & 31, tr = threadIdx.x >> 5;  // 256 threads: tr 0..7
  for (int i = tr; i < 32; i += 8) {
    int k = kb + i, n = nb + tn;
    s[i][tn] = (n < 300) ? Wu[(size_t)k * 300 + n] : 0.f;
  }
  __syncthreads();
  for (int i = tr; i < 32; i += 8) {
    int n = nb + i, k = kb + tn;
    Wt[(size_t)n * 9600 + k] = f2b(s[tn][i]);
  }
}

// ---------------- transpose [convW;W0] [1200,300] -> Wcat_t bf16 [384][1216] ----------------
__global__ void k_tr_wcat(const float* __restrict__ convW, const float* __restrict__ W0,
                          unsigned short* __restrict__ Wt) {
  __shared__ float s[32][33];
  int kb = blockIdx.x * 32, nb = blockIdx.y * 32;
  int tn = threadIdx.x & 31, tr = threadIdx.x >> 5;
  for (int i = tr; i < 32; i += 8) {
    int k = kb + i, n = nb + tn;
    float v = 0.f;
    if (n < 300 && k < 1200)
      v = (k < 900) ? convW[(size_t)k * 300 + n] : W0[(size_t)(k - 900) * 300 + n];
    s[i][tn] = v;
  }
  __syncthreads();
  for (int i = tr; i < 32; i += 8) {
    int n = nb + i, k = kb + tn;
    Wt[(size_t)n * 1216 + k] = f2b(s[tn][i]);
  }
}

// ---------------- transpose Uu [300,300] f32 -> UuT bf16 [320][320] (zero-padded) ----------------
__global__ void k_tr_uu(const float* __restrict__ Uu, unsigned short* __restrict__ UuT) {
  __shared__ float s[32][33];
  int kb = blockIdx.x * 32, nb = blockIdx.y * 32;
  int tn = threadIdx.x & 31, tr = threadIdx.x >> 5;
  for (int i = tr; i < 32; i += 8) {
    int k = kb + i, n = nb + tn;
    s[i][tn] = (k < 300 && n < 300) ? Uu[(size_t)k * 300 + n] : 0.f;
  }
  __syncthreads();
  for (int i = tr; i < 32; i += 8) {
    int n = nb + i, k = kb + tn;
    UuT[(size_t)n * 320 + k] = f2b(s[tn][i]);
  }
}

// ---------------- gather + node-0 aggregation (bf16 outputs) ----------------
__global__ void k_gather(const int* __restrict__ xidx, const int* __restrict__ esrc,
                         const int* __restrict__ edst, const float* __restrict__ X,
                         unsigned short* __restrict__ xg, unsigned short* __restrict__ Ag)
{
  const int t = blockIdx.x;
  __shared__ int s_idx[N_];
  __shared__ int s_src[R_][E_];
  __shared__ int s_dst[R_][E_];
  __shared__ int s_deg[R_][N_];
  __shared__ float s_dinv[R_][N_];
  const int tid = threadIdx.x;

  if (tid < N_) s_idx[tid] = xidx[t * N_ + tid];
  if (tid < R_ * E_) {
    int r = tid / E_, e = tid % E_;
    s_src[r][e] = esrc[(t * R_ + r) * E_ + e];
    s_dst[r][e] = edst[(t * R_ + r) * E_ + e];
  }
  if (tid < R_ * N_) ((int*)s_deg)[tid] = 1;  // self loop
  __syncthreads();
  if (tid < R_ * E_) {
    int r = tid / E_;
    atomicAdd(&s_deg[r][s_dst[r][tid % E_]], 1);
  }
  __syncthreads();
  if (tid < R_ * N_) ((float*)s_dinv)[tid] = rsqrtf((float)((int*)s_deg)[tid]);
  __syncthreads();

  for (int nd = tid; nd < N_ * D_; nd += blockDim.x) {
    int n = nd / D_, d = nd % D_;
    xg[(size_t)t * (N_ * D_) + nd] = f2b(X[(size_t)s_idx[n] * D_ + d]);
  }
  if (tid < D_) {
    int d = tid;
    float x0 = X[(size_t)s_idx[0] * D_ + d];
    #pragma unroll
    for (int r = 0; r < R_; ++r) {
      float dinv0 = s_dinv[r][0];
      float acc = dinv0 * dinv0 * x0;  // self loop
      for (int e = 0; e < E_; ++e) {
        if (s_dst[r][e] == 0) {
          int s = s_src[r][e];
          acc += s_dinv[r][s] * dinv0 * X[(size_t)s_idx[s] * D_ + d];
        }
      }
      Ag[(size_t)t * 1216 + r * D_ + d] = f2b(acc);
    }
    Ag[(size_t)t * 1216 + 900 + d] = f2b(x0);
  }
  if (tid < 16) Ag[(size_t)t * 1216 + 1200 + tid] = 0;  // K pad to 1216
}

// ---------------- bf16 MFMA GEMM: C (+)= A[M][K]bf16 @ B^T (B [Npad][K] bf16) ----------------
template<bool ATOMIC>
__global__ __launch_bounds__(256) void k_bgemm(
    const unsigned short* __restrict__ A,
    const unsigned short* __restrict__ B,
    float* __restrict__ C, int ldc, int Ncols, int K, int kchunk)
{
  const int tid = threadIdx.x;
  const int wid = tid >> 6, lane = tid & 63;
  const int l16 = lane & 15, lq = lane >> 4;
  const int bm = blockIdx.x * 128 + (wid & 1) * 64;
  const int bn = blockIdx.y * 128 + (wid >> 1) * 64;
  const int k0 = blockIdx.z * kchunk;
  const int nk = kchunk / 32;

  f32x4 acc[4][4] = {};
  const unsigned short* ap[4];
  const unsigned short* bp[4];
  #pragma unroll
  for (int mt = 0; mt < 4; ++mt) ap[mt] = A + (size_t)(bm + mt * 16 + l16) * K + k0 + lq * 8;
  #pragma unroll
  for (int nt = 0; nt < 4; ++nt) bp[nt] = B + (size_t)(bn + nt * 16 + l16) * K + k0 + lq * 8;

  #pragma unroll 2
  for (int c = 0; c < nk; ++c) {
    bf16x8 af[4], bfr[4];
    #pragma unroll
    for (int mt = 0; mt < 4; ++mt) af[mt] = *(const bf16x8*)(ap[mt] + c * 32);
    #pragma unroll
    for (int nt = 0; nt < 4; ++nt) bfr[nt] = *(const bf16x8*)(bp[nt] + c * 32);
    #pragma unroll
    for (int mt = 0; mt < 4; ++mt)
      #pragma unroll
      for (int nt = 0; nt < 4; ++nt)
        acc[mt][nt] = __builtin_amdgcn_mfma_f32_16x16x32_bf16(af[mt], bfr[nt], acc[mt][nt], 0, 0, 0);
  }

  #pragma unroll
  for (int mt = 0; mt < 4; ++mt) {
    #pragma unroll
    for (int r = 0; r < 4; ++r) {
      int row = bm + mt * 16 + lq * 4 + r;
      #pragma unroll
      for (int nt = 0; nt < 4; ++nt) {
        int col = bn + nt * 16 + l16;
        if (col < Ncols) {
          if (ATOMIC) atomicAdd(&C[(size_t)row * ldc + col], acc[mt][nt][r]);
          else        C[(size_t)row * ldc + col] = acc[mt][nt][r];
        }
      }
    }
  }
}

// ---------------- logits GEMM: out[512][40000] = Mrelu_bf[512][320] @ Wg^T + bg ----------------
__global__ __launch_bounds__(256, 2) void k_lgemm(
    const unsigned short* __restrict__ A, const float* __restrict__ Wg,
    const float* __restrict__ bg, float* __restrict__ C)
{
  const int tid = threadIdx.x;
  const int wid = tid >> 6, lane = tid & 63;
  const int l16 = lane & 15, lq = lane >> 4;
  const int bn = blockIdx.x * 64;
  const int m0 = wid * 128;

  f32x4 acc[8][4] = {};
  const unsigned short* ap[8];
  const float* bp[4];
  #pragma unroll
  for (int mt = 0; mt < 8; ++mt) ap[mt] = A + (size_t)(m0 + mt * 16 + l16) * 320 + lq * 8;
  #pragma unroll
  for (int nt = 0; nt < 4; ++nt) bp[nt] = Wg + (size_t)(bn + nt * 16 + l16) * 300;

  #pragma unroll
  for (int c = 0; c < 10; ++c) {
    bf16x8 bfr[4];
    if (c < 9) {
      #pragma unroll
      for (int nt = 0; nt < 4; ++nt) {
        f32x4 x = *(const f32x4*)(bp[nt] + c * 32 + lq * 8);
        f32x4 y = *(const f32x4*)(bp[nt] + c * 32 + lq * 8 + 4);
        bf16x8 bv;
        #pragma unroll
        for (int j = 0; j < 4; ++j) { bv[j] = (short)f2b(x[j]); bv[4 + j] = (short)f2b(y[j]); }
        bfr[nt] = bv;
      }
    } else {
      #pragma unroll
      for (int nt = 0; nt < 4; ++nt) {
        bf16x8 bv;
        #pragma unroll
        for (int j = 0; j < 8; ++j) {
          int k = 288 + lq * 8 + j;
          bv[j] = (short)((k < 300) ? f2b(bp[nt][k]) : 0);
        }
        bfr[nt] = bv;
      }
    }
    bf16x8 af[8];
    #pragma unroll
    for (int mt = 0; mt < 8; ++mt) af[mt] = *(const bf16x8*)(ap[mt] + c * 32);
    #pragma unroll
    for (int mt = 0; mt < 8; ++mt)
      #pragma unroll
      for (int nt = 0; nt < 4; ++nt)
        acc[mt][nt] = __builtin_amdgcn_mfma_f32_16x16x32_bf16(af[mt], bfr[nt], acc[mt][nt], 0, 0, 0);
  }

  float bb[4];
  #pragma unroll
  for (int nt = 0; nt < 4; ++nt) bb[nt] = bg[bn + nt * 16 + l16];
  #pragma unroll
  for (int mt = 0; mt < 8; ++mt) {
    #pragma unroll
    for (int r = 0; r < 4; ++r) {
      int row = m0 + mt * 16 + lq * 4 + r;
      #pragma unroll
      for (int nt = 0; nt < 4; ++nt) {
        int col = bn + nt * 16 + l16;
        C[(size_t)row * VG_ + col] = acc[mt][nt][r] + bb[nt];
      }
    }
  }
}

// ---------------- sequential recurrence v6: builtin MFMA + opaque-pinned B frags ----------------
// v5 post-mortem: asm-MFMA AGPR pinning was a null (inline asm is opaque to the
// scheduler/hazard recognizer -> conservative gaps ate the gain). v6 returns to
// builtin MFMA (proper hazard handling) and blocks the RA's remat-the-load
// heuristic with an empty inline asm "+v" touch on each preloaded fragment: the
// in-loop uses now trace to an un-rematerializable def, forcing true register
// residency (~200 VGPR frags, peak ~340 < 512 at 1 wave/SIMD).
// Second change: next-step gx/P0 prefetch issues at the TOP of the body into
// separate regs (gxn/p0n), rotated after the gate. Previously the gate's read of
// gxv created a WAR hazard that pinned the loads to the end of the step, so the
// L3/HBM latency (~450-900 cyc) drained at the use point; now it hides under the
// MFMA+gate phase. Col index clamped (min(c,299)) once outside the loop so loads
// carry no per-step exec-mask churn; publish keeps the exact c<300 guard.
// Numerics bit-identical (same chain order, same gate math).
__global__ __launch_bounds__(256, 1) void k_rec(
    const float* __restrict__ gx, const float* __restrict__ P0,
    const unsigned short* __restrict__ UuT, unsigned short* __restrict__ Mrelu_bf)
{
  __shared__ __align__(16) unsigned short m_bf[2][320];
  __shared__ unsigned short mr_s[16 * 320];  // 16-step Mrelu ring
  const int tid = threadIdx.x;
  const int wid = tid >> 6, lane = tid & 63;
  const int l16 = lane & 15, lq = lane >> 4;
  const int cb = wid * 80;

  // preload B fragments: bfr[nt][c] = UuT[n = cb+nt*16+l16][k = c*32+lq*8 ..+8]
  bf16x8 bfr[5][10];
  #pragma unroll
  for (int nt = 0; nt < 5; ++nt) {
    const unsigned short* bp = UuT + (size_t)(cb + nt * 16 + l16) * 320 + lq * 8;
    #pragma unroll
    for (int c = 0; c < 10; ++c)
      bfr[nt][c] = *(const bf16x8*)(bp + c * 32);
  }
  // opaque pin: kill load-rematerialization, force VGPR residency across the loop
  #pragma unroll
  for (int nt = 0; nt < 5; ++nt)
    #pragma unroll
    for (int c = 0; c < 10; ++c)
      asm("" : "+v"(bfr[nt][c]));

  // per-lane state for cols col[nt] = cb + nt*16 + l16 (redundant across lq)
  int cidx[5], cload[5];
  #pragma unroll
  for (int nt = 0; nt < 5; ++nt) {
    cidx[nt] = cb + nt * 16 + l16;
    cload[nt] = (cidx[nt] < 299) ? cidx[nt] : 299;  // clamp: always in-bounds
  }
  float mreg[5] = {0.f, 0.f, 0.f, 0.f, 0.f};
  float gxv[5], p0v[5];
  #pragma unroll
  for (int nt = 0; nt < 5; ++nt) {
    gxv[nt] = gx[cload[nt]];
    p0v[nt] = P0[cload[nt]];
  }

  const f32x4 fzero = {0.f, 0.f, 0.f, 0.f};

  for (int i = tid; i < 320; i += 256) { m_bf[0][i] = 0; m_bf[1][i] = 0; }
  for (int i = tid; i < 16 * 320; i += 256) mr_s[i] = 0;  // cols>=300 stay 0 forever
  __syncthreads();

  for (int t = 0; t < T_; ++t) {
    const int rb = t & 1, wb = rb ^ 1;
    // prefetch next step's gx/P0 FIRST (independent regs -> no WAR with the gate;
    // ~1100 cyc of ds_read+MFMA+gate below hides the L3/HBM latency)
    float gxn[5], p0n[5];
    if (t + 1 < T_) {
      const size_t o = (size_t)(t + 1) * D_;
      #pragma unroll
      for (int nt = 0; nt < 5; ++nt) {
        gxn[nt] = gx[o + cload[nt]];
        p0n[nt] = P0[o + cload[nt]];
      }
    }
    // A fragments (broadcast reads of current m): 10 ds_read_b128 per wave
    bf16x8 a[10];
    #pragma unroll
    for (int c = 0; c < 10; ++c)
      a[c] = *(const bf16x8*)(&m_bf[rb][c * 32 + lq * 8]);
    // 10 independent chains of 5 (5 tiles x 2 k-halves); C-init via fzero
    f32x4 acc0[5], acc1[5];
    #pragma unroll
    for (int nt = 0; nt < 5; ++nt) {
      acc0[nt] = __builtin_amdgcn_mfma_f32_16x16x32_bf16(a[0], bfr[nt][0], fzero, 0, 0, 0);
      acc1[nt] = __builtin_amdgcn_mfma_f32_16x16x32_bf16(a[5], bfr[nt][5], fzero, 0, 0, 0);
    }
    #pragma unroll
    for (int cc = 1; cc < 5; ++cc) {
      #pragma unroll
      for (int nt = 0; nt < 5; ++nt) {
        acc0[nt] = __builtin_amdgcn_mfma_f32_16x16x32_bf16(a[cc],     bfr[nt][cc],     acc0[nt], 0, 0, 0);
        acc1[nt] = __builtin_amdgcn_mfma_f32_16x16x32_bf16(a[cc + 5], bfr[nt][cc + 5], acc1[nt], 0, 0, 0);
      }
    }
    // gate + m update, all lanes (rows of C identical since A is broadcast)
    #pragma unroll
    for (int nt = 0; nt < 5; ++nt) {
      float z = acc0[nt][0] + acc1[nt][0] + gxv[nt];
      float g = __frcp_rn(1.f + __expf(-z));
      mreg[nt] = fmaf(g, p0v[nt] - mreg[nt], mreg[nt]);
    }
    const int slot = (t & 15) * 320;
    if (lq == 0) {
      #pragma unroll
      for (int nt = 0; nt < 5; ++nt) {
        if (cidx[nt] < 300) {
          m_bf[wb][cidx[nt]] = f2b(mreg[nt]);
          mr_s[slot + cidx[nt]] = f2b(fmaxf(mreg[nt], 0.f));
        }
      }
    }
    // rotate prefetch into current
    #pragma unroll
    for (int nt = 0; nt < 5; ++nt) { gxv[nt] = gxn[nt]; p0v[nt] = p0n[nt]; }
    LGKM_BARRIER();
    // flush 8 finished steps (rows t-7..t); slots disjoint from upcoming writes,
    // and this wave's flush reads retire before these slots are rewritten 8 steps on.
    if ((t & 7) == 7) {
      const int base = t - 7;
      const unsigned int* src = (const unsigned int*)(mr_s + (base & 15) * 320);
      unsigned int* dst = (unsigned int*)(Mrelu_bf + (size_t)base * 320);
      #pragma unroll
      for (int w = 0; w < 5; ++w) dst[tid + w * 256] = src[tid + w * 256];
    }
  }
}

// ---------------- in-place log_softmax per row + int32-zero tail ----------------
__global__ __launch_bounds__(256) void k_lsm(float* __restrict__ out) {
  const int t = blockIdx.x;
  float* row = out + (size_t)t * VG_;
  const f32x4* row4 = (const f32x4*)row;
  __shared__ float redM[256];
  __shared__ float redS[256];
  const int tid = threadIdx.x;
  float lm = -1e30f, ls = 0.f;
  for (int v = tid; v < VG_ / 4; v += 256) {
    f32x4 z4 = row4[v];
    #pragma unroll
    for (int j = 0; j < 4; ++j) {
      float z = z4[j];
      float m2 = fmaxf(lm, z);
      ls = ls * expf(lm - m2) + expf(z - m2);
      lm = m2;
    }
  }
  redM[tid] = lm; redS[tid] = ls;
  __syncthreads();
  for (int s = 128; s > 0; s >>= 1) {
    if (tid < s) {
      float mA = redM[tid], mB = redM[tid + s];
      float M = fmaxf(mA, mB);
      redS[tid] = redS[tid] * expf(mA - M) + redS[tid + s] * expf(mB - M);
      redM[tid] = M;
    }
    __syncthreads();
  }
  float lse = redM[0] + logf(redS[0]);
  f32x4* row4w = (f32x4*)row;
  for (int v = tid; v < VG_ / 4; v += 256) {
    f32x4 z4 = row4w[v];
    #pragma unroll
    for (int j = 0; j < 4; ++j) z4[j] -= lse;
    row4w[v] = z4;
  }
  if (tid == 0) out[(size_t)T_ * VG_ + t] = 0.0f;
}

// ---------------- launch ----------------
extern "C" void kernel_launch(void* const* d_in, const int* in_sizes, int n_in,
                              void* d_out, int out_size, void* d_ws, size_t ws_size,
                              hipStream_t stream) {
  const int*   xidx  = (const int*)d_in[0];
  const int*   esrc  = (const int*)d_in[1];
  const int*   edst  = (const int*)d_in[2];
  const float* X     = (const float*)d_in[3];
  const float* convW = (const float*)d_in[4];
  const float* W0    = (const float*)d_in[5];
  const float* Wu    = (const float*)d_in[6];
  const float* Uu    = (const float*)d_in[7];
  const float* Wg    = (const float*)d_in[8];
  const float* bg    = (const float*)d_in[9];
  float* out = (float*)d_out;

  // workspace layout (20.94 MB total, all 16B-aligned)
  char* ws = (char*)d_ws;
  float*          gx     = (float*)ws;                              // 512*300 f32
  float*          P0     = (float*)(ws + 614400);                   // 512*300 f32
  unsigned short* MreluB = (unsigned short*)(ws + 1228800);         // 512*320 bf16
  unsigned short* xgB    = (unsigned short*)(ws + 1556480);         // 512*9600 bf16
  unsigned short* AgB    = (unsigned short*)(ws + 11386880);        // 512*1216 bf16
  unsigned short* WuT    = (unsigned short*)(ws + 12632064);        // 384*9600 bf16
  unsigned short* WcatT  = (unsigned short*)(ws + 20004864);        // 384*1216 bf16
  // UuT bf16 [320][320] (204.8 KB) reuses the xgB region AFTER k_bgemm<true> has
  // consumed xgB (stream-ordered, no overlap with MreluB which ends at 1556480)
  unsigned short* UuT    = xgB;

  k_zero<<<(T_ * D_ + 255) / 256, 256, 0, stream>>>(gx, T_ * D_);
  k_tr_wu<<<dim3(300, 12), 256, 0, stream>>>(Wu, WuT);
  k_tr_wcat<<<dim3(38, 12), 256, 0, stream>>>(convW, W0, WcatT);
  k_gather<<<T_, 320, 0, stream>>>(xidx, esrc, edst, X, xgB, AgB);

  // gx = xg @ Wu   (split-K=10, atomic into zeroed gx)
  k_bgemm<true><<<dim3(4, 3, 10), 256, 0, stream>>>(xgB, WuT, gx, D_, D_, 9600, 960);
  // P0 = [Ag | x0] @ [convW; W0]
  k_bgemm<false><<<dim3(4, 3, 1), 256, 0, stream>>>(AgB, WcatT, P0, D_, D_, 1216, 1216);

  // xgB is dead now -> build UuT in its place, then run the recurrence
  k_tr_uu<<<dim3(10, 10), 256, 0, stream>>>(Uu, UuT);
  k_rec<<<1, 256, 0, stream>>>(gx, P0, UuT, MreluB);

  k_lgemm<<<dim3(625), 256, 0, stream>>>(MreluB, Wg, bg, out);
  k_lsm<<<T_, 256, 0, stream>>>(out);
}

// Round 4
// 811.181 us; speedup vs baseline: 1.1836x; 1.1836x over previous
//
#include <hip/hip_runtime.h>
#include <hip/hip_bf16.h>
#include <math.h>

#define T_ 512
#define N_ 32
#define D_ 300
#define R_ 3
#define E_ 64
#define VG_ 40000

typedef __attribute__((ext_vector_type(8))) short bf16x8;
typedef __attribute__((ext_vector_type(4))) float f32x4;

// barrier with lgkm-only wait (raw asm barrier: no forced vmcnt drain here —
// global prefetch loads stay in flight across the barrier)
#define LGKM_BARRIER() asm volatile("s_waitcnt lgkmcnt(0)\n\ts_barrier" ::: "memory")

static __device__ inline unsigned short f2b(float f) {
  __hip_bfloat16 h = __float2bfloat16(f);
  return *(unsigned short*)&h;
}

// ---------------- zero ----------------
__global__ void k_zero(float* __restrict__ p, int n) {
  int i = blockIdx.x * blockDim.x + threadIdx.x;
  if (i < n) p[i] = 0.f;
}

// ---------------- transpose Wu [9600,300] -> Wu_t bf16 [384][9600] ----------------
__global__ void k_tr_wu(const float* __restrict__ Wu, unsigned short* __restrict__ Wt) {
  __shared__ float s[32][33];
  int kb = blockIdx.x * 32, nb = blockIdx.y * 32;
  int tn = threadIdx.x & 31, tr = threadIdx.x >> 5;  // 256 threads: tr 0..7
  for (int i = tr; i < 32; i += 8) {
    int k = kb + i, n = nb + tn;
    s[i][tn] = (n < 300) ? Wu[(size_t)k * 300 + n] : 0.f;
  }
  __syncthreads();
  for (int i = tr; i < 32; i += 8) {
    int n = nb + i, k = kb + tn;
    Wt[(size_t)n * 9600 + k] = f2b(s[tn][i]);
  }
}

// ---------------- transpose [convW;W0] [1200,300] -> Wcat_t bf16 [384][1216] ----------------
__global__ void k_tr_wcat(const float* __restrict__ convW, const float* __restrict__ W0,
                          unsigned short* __restrict__ Wt) {
  __shared__ float s[32][33];
  int kb = blockIdx.x * 32, nb = blockIdx.y * 32;
  int tn = threadIdx.x & 31, tr = threadIdx.x >> 5;
  for (int i = tr; i < 32; i += 8) {
    int k = kb + i, n = nb + tn;
    float v = 0.f;
    if (n < 300 && k < 1200)
      v = (k < 900) ? convW[(size_t)k * 300 + n] : W0[(size_t)(k - 900) * 300 + n];
    s[i][tn] = v;
  }
  __syncthreads();
  for (int i = tr; i < 32; i += 8) {
    int n = nb + i, k = kb + tn;
    Wt[(size_t)n * 1216 + k] = f2b(s[tn][i]);
  }
}

// ---------------- transpose Uu [300,300] f32 -> UuT bf16 [320][320] (zero-padded) ----------------
__global__ void k_tr_uu(const float* __restrict__ Uu, unsigned short* __restrict__ UuT) {
  __shared__ float s[32][33];
  int kb = blockIdx.x * 32, nb = blockIdx.y * 32;
  int tn = threadIdx.x & 31, tr = threadIdx.x >> 5;
  for (int i = tr; i < 32; i += 8) {
    int k = kb + i, n = nb + tn;
    s[i][tn] = (k < 300 && n < 300) ? Uu[(size_t)k * 300 + n] : 0.f;
  }
  __syncthreads();
  for (int i = tr; i < 32; i += 8) {
    int n = nb + i, k = kb + tn;
    UuT[(size_t)n * 320 + k] = f2b(s[tn][i]);
  }
}

// ---------------- gather + node-0 aggregation (bf16 outputs) ----------------
__global__ void k_gather(const int* __restrict__ xidx, const int* __restrict__ esrc,
                         const int* __restrict__ edst, const float* __restrict__ X,
                         unsigned short* __restrict__ xg, unsigned short* __restrict__ Ag)
{
  const int t = blockIdx.x;
  __shared__ int s_idx[N_];
  __shared__ int s_src[R_][E_];
  __shared__ int s_dst[R_][E_];
  __shared__ int s_deg[R_][N_];
  __shared__ float s_dinv[R_][N_];
  const int tid = threadIdx.x;

  if (tid < N_) s_idx[tid] = xidx[t * N_ + tid];
  if (tid < R_ * E_) {
    int r = tid / E_, e = tid % E_;
    s_src[r][e] = esrc[(t * R_ + r) * E_ + e];
    s_dst[r][e] = edst[(t * R_ + r) * E_ + e];
  }
  if (tid < R_ * N_) ((int*)s_deg)[tid] = 1;  // self loop
  __syncthreads();
  if (tid < R_ * E_) {
    int r = tid / E_;
    atomicAdd(&s_deg[r][s_dst[r][tid % E_]], 1);
  }
  __syncthreads();
  if (tid < R_ * N_) ((float*)s_dinv)[tid] = rsqrtf((float)((int*)s_deg)[tid]);
  __syncthreads();

  for (int nd = tid; nd < N_ * D_; nd += blockDim.x) {
    int n = nd / D_, d = nd % D_;
    xg[(size_t)t * (N_ * D_) + nd] = f2b(X[(size_t)s_idx[n] * D_ + d]);
  }
  if (tid < D_) {
    int d = tid;
    float x0 = X[(size_t)s_idx[0] * D_ + d];
    #pragma unroll
    for (int r = 0; r < R_; ++r) {
      float dinv0 = s_dinv[r][0];
      float acc = dinv0 * dinv0 * x0;  // self loop
      for (int e = 0; e < E_; ++e) {
        if (s_dst[r][e] == 0) {
          int s = s_src[r][e];
          acc += s_dinv[r][s] * dinv0 * X[(size_t)s_idx[s] * D_ + d];
        }
      }
      Ag[(size_t)t * 1216 + r * D_ + d] = f2b(acc);
    }
    Ag[(size_t)t * 1216 + 900 + d] = f2b(x0);
  }
  if (tid < 16) Ag[(size_t)t * 1216 + 1200 + tid] = 0;  // K pad to 1216
}

// ---------------- bf16 MFMA GEMM: C (+)= A[M][K]bf16 @ B^T (B [Npad][K] bf16) ----------------
template<bool ATOMIC>
__global__ __launch_bounds__(256) void k_bgemm(
    const unsigned short* __restrict__ A,
    const unsigned short* __restrict__ B,
    float* __restrict__ C, int ldc, int Ncols, int K, int kchunk)
{
  const int tid = threadIdx.x;
  const int wid = tid >> 6, lane = tid & 63;
  const int l16 = lane & 15, lq = lane >> 4;
  const int bm = blockIdx.x * 128 + (wid & 1) * 64;
  const int bn = blockIdx.y * 128 + (wid >> 1) * 64;
  const int k0 = blockIdx.z * kchunk;
  const int nk = kchunk / 32;

  f32x4 acc[4][4] = {};
  const unsigned short* ap[4];
  const unsigned short* bp[4];
  #pragma unroll
  for (int mt = 0; mt < 4; ++mt) ap[mt] = A + (size_t)(bm + mt * 16 + l16) * K + k0 + lq * 8;
  #pragma unroll
  for (int nt = 0; nt < 4; ++nt) bp[nt] = B + (size_t)(bn + nt * 16 + l16) * K + k0 + lq * 8;

  #pragma unroll 2
  for (int c = 0; c < nk; ++c) {
    bf16x8 af[4], bfr[4];
    #pragma unroll
    for (int mt = 0; mt < 4; ++mt) af[mt] = *(const bf16x8*)(ap[mt] + c * 32);
    #pragma unroll
    for (int nt = 0; nt < 4; ++nt) bfr[nt] = *(const bf16x8*)(bp[nt] + c * 32);
    #pragma unroll
    for (int mt = 0; mt < 4; ++mt)
      #pragma unroll
      for (int nt = 0; nt < 4; ++nt)
        acc[mt][nt] = __builtin_amdgcn_mfma_f32_16x16x32_bf16(af[mt], bfr[nt], acc[mt][nt], 0, 0, 0);
  }

  #pragma unroll
  for (int mt = 0; mt < 4; ++mt) {
    #pragma unroll
    for (int r = 0; r < 4; ++r) {
      int row = bm + mt * 16 + lq * 4 + r;
      #pragma unroll
      for (int nt = 0; nt < 4; ++nt) {
        int col = bn + nt * 16 + l16;
        if (col < Ncols) {
          if (ATOMIC) atomicAdd(&C[(size_t)row * ldc + col], acc[mt][nt][r]);
          else        C[(size_t)row * ldc + col] = acc[mt][nt][r];
        }
      }
    }
  }
}

// ---------------- logits GEMM: out[512][40000] = Mrelu_bf[512][320] @ Wg^T + bg ----------------
__global__ __launch_bounds__(256, 2) void k_lgemm(
    const unsigned short* __restrict__ A, const float* __restrict__ Wg,
    const float* __restrict__ bg, float* __restrict__ C)
{
  const int tid = threadIdx.x;
  const int wid = tid >> 6, lane = tid & 63;
  const int l16 = lane & 15, lq = lane >> 4;
  const int bn = blockIdx.x * 64;
  const int m0 = wid * 128;

  f32x4 acc[8][4] = {};
  const unsigned short* ap[8];
  const float* bp[4];
  #pragma unroll
  for (int mt = 0; mt < 8; ++mt) ap[mt] = A + (size_t)(m0 + mt * 16 + l16) * 320 + lq * 8;
  #pragma unroll
  for (int nt = 0; nt < 4; ++nt) bp[nt] = Wg + (size_t)(bn + nt * 16 + l16) * 300;

  #pragma unroll
  for (int c = 0; c < 10; ++c) {
    bf16x8 bfr[4];
    if (c < 9) {
      #pragma unroll
      for (int nt = 0; nt < 4; ++nt) {
        f32x4 x = *(const f32x4*)(bp[nt] + c * 32 + lq * 8);
        f32x4 y = *(const f32x4*)(bp[nt] + c * 32 + lq * 8 + 4);
        bf16x8 bv;
        #pragma unroll
        for (int j = 0; j < 4; ++j) { bv[j] = (short)f2b(x[j]); bv[4 + j] = (short)f2b(y[j]); }
        bfr[nt] = bv;
      }
    } else {
      #pragma unroll
      for (int nt = 0; nt < 4; ++nt) {
        bf16x8 bv;
        #pragma unroll
        for (int j = 0; j < 8; ++j) {
          int k = 288 + lq * 8 + j;
          bv[j] = (short)((k < 300) ? f2b(bp[nt][k]) : 0);
        }
        bfr[nt] = bv;
      }
    }
    bf16x8 af[8];
    #pragma unroll
    for (int mt = 0; mt < 8; ++mt) af[mt] = *(const bf16x8*)(ap[mt] + c * 32);
    #pragma unroll
    for (int mt = 0; mt < 8; ++mt)
      #pragma unroll
      for (int nt = 0; nt < 4; ++nt)
        acc[mt][nt] = __builtin_amdgcn_mfma_f32_16x16x32_bf16(af[mt], bfr[nt], acc[mt][nt], 0, 0, 0);
  }

  float bb[4];
  #pragma unroll
  for (int nt = 0; nt < 4; ++nt) bb[nt] = bg[bn + nt * 16 + l16];
  #pragma unroll
  for (int mt = 0; mt < 8; ++mt) {
    #pragma unroll
    for (int r = 0; r < 4; ++r) {
      int row = m0 + mt * 16 + lq * 4 + r;
      #pragma unroll
      for (int nt = 0; nt < 4; ++nt) {
        int col = bn + nt * 16 + l16;
        C[(size_t)row * VG_ + col] = acc[mt][nt][r] + bb[nt];
      }
    }
  }
}

// ---------------- sequential recurrence v7: multi-wave pipe fill + VGPR-resident frags ----------------
// Unified post-mortem of v3..v6: FETCH_SIZE never moved (~706KB) -> fragments were
// never re-fetched from memory; the invariant ~30% VALUBusy was v_accvgpr_read
// copies (frags parked in AGPRs at VGPR_Count 144-156) resp. scalar-load remat in
// v3; and v4-v6's extra regression vs v3 shows a SINGLE wave per SIMD cannot
// sustain the MFMA pipe (effective ~2x issue interval). No version had BOTH
// multi-wave pipe filling AND arch-VGPR-resident fragments. v7 does:
//   - 640 threads = 10 waves (3/3/2/2 per SIMD) -> multi-wave MFMA issue overlap
//   - 2 tiles/wave -> 20 frag regs... 2x10x4 = 80 VGPR frags + 40 A + 16 acc
//     + ~20 state ~= 158 regs
//   - __launch_bounds__(640, 3): RA budget 512/3 ~= 168 VGPRs -> fits in arch
//     VGPRs (v3's budget was 84 -> remat hell)
//   - opaque pin keeps the RA from remat'ing; builtin MFMA keeps hazard handling
// Numerics bit-identical (same chain order: 2 k-half chains per tile, same gate).
__global__ __launch_bounds__(640, 3) void k_rec(
    const float* __restrict__ gx, const float* __restrict__ P0,
    const unsigned short* __restrict__ UuT, unsigned short* __restrict__ Mrelu_bf)
{
  __shared__ __align__(16) unsigned short m_bf[2][320];
  __shared__ unsigned short mr_s[16 * 320];  // 16-step Mrelu ring
  const int tid = threadIdx.x;
  const int wid = tid >> 6, lane = tid & 63;
  const int l16 = lane & 15, lq = lane >> 4;

  // wave wid owns col-tiles {2wid, 2wid+1} = cols [32wid, 32wid+32)
  const int c0 = wid * 32 + l16;
  const int c1 = c0 + 16;

  // preload B fragments: bfr[nt][c] = UuT[n][k = c*32+lq*8 ..+8], n = c0 / c1
  bf16x8 bfr[2][10];
  {
    const unsigned short* bp0 = UuT + (size_t)c0 * 320 + lq * 8;
    const unsigned short* bp1 = UuT + (size_t)c1 * 320 + lq * 8;
    #pragma unroll
    for (int c = 0; c < 10; ++c) {
      bfr[0][c] = *(const bf16x8*)(bp0 + c * 32);
      bfr[1][c] = *(const bf16x8*)(bp1 + c * 32);
    }
  }
  // opaque pin: block load-remat; with the 168-reg budget these stay arch-VGPR
  #pragma unroll
  for (int nt = 0; nt < 2; ++nt)
    #pragma unroll
    for (int c = 0; c < 10; ++c)
      asm("" : "+v"(bfr[nt][c]));

  const int cl0 = (c0 < 299) ? c0 : 299;  // clamped load idx (always in-bounds)
  const int cl1 = (c1 < 299) ? c1 : 299;
  float m0 = 0.f, m1 = 0.f;
  float gx0 = gx[cl0], gx1 = gx[cl1];
  float p00 = P0[cl0], p01 = P0[cl1];

  const f32x4 fzero = {0.f, 0.f, 0.f, 0.f};

  for (int i = tid; i < 320; i += 640) { m_bf[0][i] = 0; m_bf[1][i] = 0; }
  for (int i = tid; i < 16 * 320; i += 640) mr_s[i] = 0;  // cols>=300 stay 0 forever
  __syncthreads();

  for (int t = 0; t < T_; ++t) {
    const int rb = t & 1, wb = rb ^ 1;
    // prefetch next step's gx/P0 first (independent regs; latency hides under MFMA)
    float gxn0, gxn1, p0n0, p0n1;
    if (t + 1 < T_) {
      const size_t o = (size_t)(t + 1) * D_;
      gxn0 = gx[o + cl0]; gxn1 = gx[o + cl1];
      p0n0 = P0[o + cl0]; p0n1 = P0[o + cl1];
    }
    // A fragments (broadcast reads of current m): 10 ds_read_b128 per wave
    bf16x8 a[10];
    #pragma unroll
    for (int c = 0; c < 10; ++c)
      a[c] = *(const bf16x8*)(&m_bf[rb][c * 32 + lq * 8]);
    // 4 chains (2 tiles x 2 k-halves); C-init via fzero
    f32x4 A0, A1, B0, B1;
    A0 = __builtin_amdgcn_mfma_f32_16x16x32_bf16(a[0], bfr[0][0], fzero, 0, 0, 0);
    A1 = __builtin_amdgcn_mfma_f32_16x16x32_bf16(a[0], bfr[1][0], fzero, 0, 0, 0);
    B0 = __builtin_amdgcn_mfma_f32_16x16x32_bf16(a[5], bfr[0][5], fzero, 0, 0, 0);
    B1 = __builtin_amdgcn_mfma_f32_16x16x32_bf16(a[5], bfr[1][5], fzero, 0, 0, 0);
    #pragma unroll
    for (int cc = 1; cc < 5; ++cc) {
      A0 = __builtin_amdgcn_mfma_f32_16x16x32_bf16(a[cc],     bfr[0][cc],     A0, 0, 0, 0);
      A1 = __builtin_amdgcn_mfma_f32_16x16x32_bf16(a[cc],     bfr[1][cc],     A1, 0, 0, 0);
      B0 = __builtin_amdgcn_mfma_f32_16x16x32_bf16(a[cc + 5], bfr[0][cc + 5], B0, 0, 0, 0);
      B1 = __builtin_amdgcn_mfma_f32_16x16x32_bf16(a[cc + 5], bfr[1][cc + 5], B1, 0, 0, 0);
    }
    // gate + m update, all lanes (rows of C identical since A is broadcast);
    // z = k-half0 + k-half1 + gx  (same order as previous versions)
    {
      float z0 = A0[0] + B0[0] + gx0;
      float g0 = __frcp_rn(1.f + __expf(-z0));
      m0 = fmaf(g0, p00 - m0, m0);
      float z1 = A1[0] + B1[0] + gx1;
      float g1 = __frcp_rn(1.f + __expf(-z1));
      m1 = fmaf(g1, p01 - m1, m1);
    }
    const int slot = (t & 15) * 320;
    if (lq == 0) {
      if (c0 < 300) {
        m_bf[wb][c0] = f2b(m0);
        mr_s[slot + c0] = f2b(fmaxf(m0, 0.f));
      }
      if (c1 < 300) {
        m_bf[wb][c1] = f2b(m1);
        mr_s[slot + c1] = f2b(fmaxf(m1, 0.f));
      }
    }
    // rotate prefetch into current
    gx0 = gxn0; gx1 = gxn1; p00 = p0n0; p01 = p0n1;
    LGKM_BARRIER();
    // flush 8 finished steps (rows t-7..t); slots disjoint from upcoming writes,
    // and this wave's flush reads retire before these slots are rewritten 8 steps on.
    if ((t & 7) == 7) {
      const int base = t - 7;
      const unsigned int* src = (const unsigned int*)(mr_s + (base & 15) * 320);
      unsigned int* dst = (unsigned int*)(Mrelu_bf + (size_t)base * 320);
      #pragma unroll
      for (int w = 0; w < 2; ++w) dst[tid + w * 640] = src[tid + w * 640];
    }
  }
}

// ---------------- in-place log_softmax per row + int32-zero tail ----------------
__global__ __launch_bounds__(256) void k_lsm(float* __restrict__ out) {
  const int t = blockIdx.x;
  float* row = out + (size_t)t * VG_;
  const f32x4* row4 = (const f32x4*)row;
  __shared__ float redM[256];
  __shared__ float redS[256];
  const int tid = threadIdx.x;
  float lm = -1e30f, ls = 0.f;
  for (int v = tid; v < VG_ / 4; v += 256) {
    f32x4 z4 = row4[v];
    #pragma unroll
    for (int j = 0; j < 4; ++j) {
      float z = z4[j];
      float m2 = fmaxf(lm, z);
      ls = ls * expf(lm - m2) + expf(z - m2);
      lm = m2;
    }
  }
  redM[tid] = lm; redS[tid] = ls;
  __syncthreads();
  for (int s = 128; s > 0; s >>= 1) {
    if (tid < s) {
      float mA = redM[tid], mB = redM[tid + s];
      float M = fmaxf(mA, mB);
      redS[tid] = redS[tid] * expf(mA - M) + redS[tid + s] * expf(mB - M);
      redM[tid] = M;
    }
    __syncthreads();
  }
  float lse = redM[0] + logf(redS[0]);
  f32x4* row4w = (f32x4*)row;
  for (int v = tid; v < VG_ / 4; v += 256) {
    f32x4 z4 = row4w[v];
    #pragma unroll
    for (int j = 0; j < 4; ++j) z4[j] -= lse;
    row4w[v] = z4;
  }
  if (tid == 0) out[(size_t)T_ * VG_ + t] = 0.0f;
}

// ---------------- launch ----------------
extern "C" void kernel_launch(void* const* d_in, const int* in_sizes, int n_in,
                              void* d_out, int out_size, void* d_ws, size_t ws_size,
                              hipStream_t stream) {
  const int*   xidx  = (const int*)d_in[0];
  const int*   esrc  = (const int*)d_in[1];
  const int*   edst  = (const int*)d_in[2];
  const float* X     = (const float*)d_in[3];
  const float* convW = (const float*)d_in[4];
  const float* W0    = (const float*)d_in[5];
  const float* Wu    = (const float*)d_in[6];
  const float* Uu    = (const float*)d_in[7];
  const float* Wg    = (const float*)d_in[8];
  const float* bg    = (const float*)d_in[9];
  float* out = (float*)d_out;

  // workspace layout (20.94 MB total, all 16B-aligned)
  char* ws = (char*)d_ws;
  float*          gx     = (float*)ws;                              // 512*300 f32
  float*          P0     = (float*)(ws + 614400);                   // 512*300 f32
  unsigned short* MreluB = (unsigned short*)(ws + 1228800);         // 512*320 bf16
  unsigned short* xgB    = (unsigned short*)(ws + 1556480);         // 512*9600 bf16
  unsigned short* AgB    = (unsigned short*)(ws + 11386880);        // 512*1216 bf16
  unsigned short* WuT    = (unsigned short*)(ws + 12632064);        // 384*9600 bf16
  unsigned short* WcatT  = (unsigned short*)(ws + 20004864);        // 384*1216 bf16
  // UuT bf16 [320][320] (204.8 KB) reuses the xgB region AFTER k_bgemm<true> has
  // consumed xgB (stream-ordered, no overlap with MreluB which ends at 1556480)
  unsigned short* UuT    = xgB;

  k_zero<<<(T_ * D_ + 255) / 256, 256, 0, stream>>>(gx, T_ * D_);
  k_tr_wu<<<dim3(300, 12), 256, 0, stream>>>(Wu, WuT);
  k_tr_wcat<<<dim3(38, 12), 256, 0, stream>>>(convW, W0, WcatT);
  k_gather<<<T_, 320, 0, stream>>>(xidx, esrc, edst, X, xgB, AgB);

  // gx = xg @ Wu   (split-K=10, atomic into zeroed gx)
  k_bgemm<true><<<dim3(4, 3, 10), 256, 0, stream>>>(xgB, WuT, gx, D_, D_, 9600, 960);
  // P0 = [Ag | x0] @ [convW; W0]
  k_bgemm<false><<<dim3(4, 3, 1), 256, 0, stream>>>(AgB, WcatT, P0, D_, D_, 1216, 1216);

  // xgB is dead now -> build UuT in its place, then run the recurrence
  k_tr_uu<<<dim3(10, 10), 256, 0, stream>>>(Uu, UuT);
  k_rec<<<1, 640, 0, stream>>>(gx, P0, UuT, MreluB);

  k_lgemm<<<dim3(625), 256, 0, stream>>>(MreluB, Wg, bg, out);
  k_lsm<<<T_, 256, 0, stream>>>(out);
}